// Round 3
// baseline (5207.648 us; speedup 1.0000x reference)
//
#include <hip/hip_runtime.h>
#include <stdint.h>

#define S 2048
#define E 2048
#define NH 16
#define NG 4
#define HD 128
// rep = NH/NG = 4, head h uses kv group h>>2

// C[M,N] = A[M,K] @ B[K,N], all fp32. 64x64 tile, BK=16, 256 thr, 4x4/thread.
__global__ __launch_bounds__(256) void gemm_f32(const float* __restrict__ A,
                                                const float* __restrict__ B,
                                                float* __restrict__ C,
                                                int M, int N, int K)
{
    __shared__ float As[64][16];
    __shared__ float Bs[16][64];
    int tid = threadIdx.x;
    int tx = tid & 15, ty = tid >> 4;
    int row0 = blockIdx.y * 64, col0 = blockIdx.x * 64;
    float acc[4][4] = {};
    int ae = tid * 4; int ar = ae >> 4, ac = ae & 15;
    int be = tid * 4; int br = be >> 6, bc = be & 63;
    for (int k0 = 0; k0 < K; k0 += 16) {
        float4 av = *(const float4*)(A + (size_t)(row0 + ar) * K + k0 + ac);
        float4 bv = *(const float4*)(B + (size_t)(k0 + br) * N + col0 + bc);
        As[ar][ac + 0] = av.x; As[ar][ac + 1] = av.y;
        As[ar][ac + 2] = av.z; As[ar][ac + 3] = av.w;
        Bs[br][bc + 0] = bv.x; Bs[br][bc + 1] = bv.y;
        Bs[br][bc + 2] = bv.z; Bs[br][bc + 3] = bv.w;
        __syncthreads();
        #pragma unroll
        for (int kk = 0; kk < 16; kk++) {
            float a[4], b[4];
            #pragma unroll
            for (int i = 0; i < 4; i++) a[i] = As[ty * 4 + i][kk];
            #pragma unroll
            for (int j = 0; j < 4; j++) b[j] = Bs[kk][tx * 4 + j];
            #pragma unroll
            for (int i = 0; i < 4; i++)
                #pragma unroll
                for (int j = 0; j < 4; j++) acc[i][j] += a[i] * b[j];
        }
        __syncthreads();
    }
    #pragma unroll
    for (int i = 0; i < 4; i++) {
        float4 ov = make_float4(acc[i][0], acc[i][1], acc[i][2], acc[i][3]);
        *(float4*)(C + (size_t)(row0 + ty * 4 + i) * N + col0 + tx * 4) = ov;
    }
}

// In-place RoPE on T: (S, nHeads, HD) fp32. idx = s*nHeads*64 + head*64 + d, d<64.
__global__ void rope_kernel(float* __restrict__ T,
                            const float* __restrict__ cosp,
                            const float* __restrict__ sinp,
                            int nHeads, int total)
{
    int idx = blockIdx.x * blockDim.x + threadIdx.x;
    if (idx >= total) return;
    int d = idx & 63;
    int head = (idx >> 6) % nHeads;
    int s = idx / (nHeads * 64);
    float c  = cosp[s * HD + d];   // cos[s][d] == cos[s][d+64]
    float sn = sinp[s * HD + d];
    size_t base = (size_t)s * nHeads * HD + head * HD + d;
    float x1 = T[base], x2 = T[base + 64];
    T[base]      = x1 * c - x2 * sn;
    T[base + 64] = x2 * c + x1 * sn;
}

// One block per (query i, head h). Causal softmax + p write (fp32) + o accumulation.
__global__ __launch_bounds__(256) void attn_kernel(const float* __restrict__ Q,
                                                   const float* __restrict__ K,
                                                   const float* __restrict__ V,
                                                   float* __restrict__ P,
                                                   float* __restrict__ O)
{
    __shared__ float sc[S];
    __shared__ float qs[HD];
    __shared__ float red[256];
    __shared__ float opart[256];
    int i = blockIdx.x, h = blockIdx.y, g = h >> 2;
    int tid = threadIdx.x;
    if (tid < HD) qs[tid] = Q[(size_t)i * E + h * HD + tid];
    __syncthreads();
    const float scale = 0.08838834764831845f;  // 1/sqrt(128)
    float m = -1e30f;
    for (int j = tid; j <= i; j += 256) {
        const float* kp = K + (size_t)j * (NG * HD) + g * HD;
        float acc = 0.f;
        #pragma unroll
        for (int d = 0; d < HD; d += 4) {
            float4 kv = *(const float4*)(kp + d);
            float4 qv = *(const float4*)(qs + d);
            acc += qv.x * kv.x + qv.y * kv.y + qv.z * kv.z + qv.w * kv.w;
        }
        float sv = acc * scale;
        sc[j] = sv;
        m = fmaxf(m, sv);
    }
    red[tid] = m; __syncthreads();
    for (int st = 128; st > 0; st >>= 1) {
        if (tid < st) red[tid] = fmaxf(red[tid], red[tid + st]);
        __syncthreads();
    }
    m = red[0]; __syncthreads();
    float sum = 0.f;
    for (int j = tid; j <= i; j += 256) {
        float e = __expf(sc[j] - m);
        sc[j] = e; sum += e;
    }
    red[tid] = sum; __syncthreads();
    for (int st = 128; st > 0; st >>= 1) {
        if (tid < st) red[tid] += red[tid + st];
        __syncthreads();
    }
    float inv = 1.0f / red[0];
    // p row: (h, i, :) fp32, zeros above the diagonal; float4 stores.
    float* prow = P + ((size_t)h * S + i) * S;
    for (int b = tid * 4; b < S; b += 1024) {
        float4 pv;
        pv.x = (b     <= i) ? sc[b]     * inv : 0.0f;
        pv.y = (b + 1 <= i) ? sc[b + 1] * inv : 0.0f;
        pv.z = (b + 2 <= i) ? sc[b + 2] * inv : 0.0f;
        pv.w = (b + 3 <= i) ? sc[b + 3] * inv : 0.0f;
        *(float4*)(prow + b) = pv;
    }
    // o = (sum_j e_j * v_j) * inv ; split j over 2 halves of the block.
    int d = tid & 127, half = tid >> 7;
    float acc = 0.f;
    for (int j = half; j <= i; j += 2)
        acc += sc[j] * V[(size_t)j * (NG * HD) + g * HD + d];
    opart[tid] = acc; __syncthreads();
    if (tid < HD)
        O[(size_t)i * E + h * HD + tid] = (opart[tid] + opart[tid + HD]) * inv;
}

extern "C" void kernel_launch(void* const* d_in, const int* in_sizes, int n_in,
                              void* d_out, int out_size, void* d_ws, size_t ws_size,
                              hipStream_t stream)
{
    const float* x    = (const float*)d_in[0];
    // d_in[1] = mask: causal triu(k=1), implemented analytically — unused.
    const float* cosp = (const float*)d_in[2];
    const float* sinp = (const float*)d_in[3];
    const float* Wq   = (const float*)d_in[4];
    const float* Wk   = (const float*)d_in[5];
    const float* Wv   = (const float*)d_in[6];
    const float* Wout = (const float*)d_in[7];

    float* out0 = (float*)d_out;               // (S, E) fp32
    float* Pout = out0 + (size_t)S * E;        // (NH, S, S) fp32

    float* Qb = (float*)d_ws;                  // S*E        fp32 (16 MB)
    float* Kb = Qb + (size_t)S * E;            // S*NG*HD    fp32 ( 4 MB)
    float* Vb = Kb + (size_t)S * NG * HD;      // S*NG*HD    fp32 ( 4 MB)
    float* Ob = Vb + (size_t)S * NG * HD;      // S*E        fp32 (16 MB)

    dim3 blk(256);
    gemm_f32<<<dim3(E / 64, S / 64), blk, 0, stream>>>(x, Wq, Qb, S, E, E);
    gemm_f32<<<dim3((NG * HD) / 64, S / 64), blk, 0, stream>>>(x, Wk, Kb, S, NG * HD, E);
    gemm_f32<<<dim3((NG * HD) / 64, S / 64), blk, 0, stream>>>(x, Wv, Vb, S, NG * HD, E);

    int totQ = S * NH * 64;
    rope_kernel<<<(totQ + 255) / 256, blk, 0, stream>>>(Qb, cosp, sinp, NH, totQ);
    int totK = S * NG * 64;
    rope_kernel<<<(totK + 255) / 256, blk, 0, stream>>>(Kb, cosp, sinp, NG, totK);

    attn_kernel<<<dim3(S, NH), blk, 0, stream>>>(Qb, Kb, Vb, Pout, Ob);

    gemm_f32<<<dim3(E / 64, S / 64), blk, 0, stream>>>(Ob, Wout, out0, S, E, E);
}

// Round 4
// 1800.333 us; speedup vs baseline: 2.8926x; 2.8926x over previous
//
#include <hip/hip_runtime.h>
#include <stdint.h>

#define S 2048
#define E 2048
#define NH 16
#define NG 4
#define HD 128
// rep = NH/NG = 4, head h uses kv group h>>2

// C[M,N] = A[M,K] @ B[K,N], all fp32. 64x64 tile, BK=16, 256 thr, 4x4/thread.
__global__ __launch_bounds__(256) void gemm_f32(const float* __restrict__ A,
                                                const float* __restrict__ B,
                                                float* __restrict__ C,
                                                int M, int N, int K)
{
    __shared__ float As[64][16];
    __shared__ float Bs[16][64];
    int tid = threadIdx.x;
    int tx = tid & 15, ty = tid >> 4;
    int row0 = blockIdx.y * 64, col0 = blockIdx.x * 64;
    float acc[4][4] = {};
    int ae = tid * 4; int ar = ae >> 4, ac = ae & 15;
    int be = tid * 4; int br = be >> 6, bc = be & 63;
    for (int k0 = 0; k0 < K; k0 += 16) {
        float4 av = *(const float4*)(A + (size_t)(row0 + ar) * K + k0 + ac);
        float4 bv = *(const float4*)(B + (size_t)(k0 + br) * N + col0 + bc);
        As[ar][ac + 0] = av.x; As[ar][ac + 1] = av.y;
        As[ar][ac + 2] = av.z; As[ar][ac + 3] = av.w;
        Bs[br][bc + 0] = bv.x; Bs[br][bc + 1] = bv.y;
        Bs[br][bc + 2] = bv.z; Bs[br][bc + 3] = bv.w;
        __syncthreads();
        #pragma unroll
        for (int kk = 0; kk < 16; kk++) {
            float a[4], b[4];
            #pragma unroll
            for (int i = 0; i < 4; i++) a[i] = As[ty * 4 + i][kk];
            #pragma unroll
            for (int j = 0; j < 4; j++) b[j] = Bs[kk][tx * 4 + j];
            #pragma unroll
            for (int i = 0; i < 4; i++)
                #pragma unroll
                for (int j = 0; j < 4; j++) acc[i][j] += a[i] * b[j];
        }
        __syncthreads();
    }
    #pragma unroll
    for (int i = 0; i < 4; i++) {
        float4 ov = make_float4(acc[i][0], acc[i][1], acc[i][2], acc[i][3]);
        *(float4*)(C + (size_t)(row0 + ty * 4 + i) * N + col0 + tx * 4) = ov;
    }
}

// In-place RoPE on T: (S, nHeads, HD) fp32. idx = s*nHeads*64 + head*64 + d, d<64.
__global__ void rope_kernel(float* __restrict__ T,
                            const float* __restrict__ cosp,
                            const float* __restrict__ sinp,
                            int nHeads, int total)
{
    int idx = blockIdx.x * blockDim.x + threadIdx.x;
    if (idx >= total) return;
    int d = idx & 63;
    int head = (idx >> 6) % nHeads;
    int s = idx / (nHeads * 64);
    float c  = cosp[s * HD + d];   // cos[s][d] == cos[s][d+64]
    float sn = sinp[s * HD + d];
    size_t base = (size_t)s * nHeads * HD + head * HD + d;
    float x1 = T[base], x2 = T[base + 64];
    T[base]      = x1 * c - x2 * sn;
    T[base + 64] = x2 * c + x1 * sn;
}

// Raw scores: P[h][i][j] = (Q_h[i] . K_g[j]) * scale for causal-touching 64x64 tiles.
// Tiles with j0 > i0 are skipped entirely (softmax writes zeros there).
__global__ __launch_bounds__(256) void score_kernel(const float* __restrict__ Q,
                                                    const float* __restrict__ K,
                                                    float* __restrict__ P)
{
    int jt = blockIdx.x, it = blockIdx.y, h = blockIdx.z;
    if (jt > it) return;
    int g = h >> 2;
    int i0 = it * 64, j0 = jt * 64;
    __shared__ float As[64][17];   // As[i][kk]
    __shared__ float Bs[16][65];   // Bs[kk][j]  (padded: transposed fill)
    int tid = threadIdx.x;
    int tx = tid & 15, ty = tid >> 4;
    float acc[4][4] = {};
    int ae = tid * 4; int ar = ae >> 4, ac = ae & 15;   // A fill: row ar, cols ac..ac+3
    int jr = tid >> 2, c4 = (tid & 3) * 4;              // B fill: K row jr, k-chunk c4
    const float scale = 0.08838834764831845f;  // 1/sqrt(128)
    for (int k0 = 0; k0 < HD; k0 += 16) {
        float4 av = *(const float4*)(Q + (size_t)(i0 + ar) * E + h * HD + k0 + ac);
        float4 bv = *(const float4*)(K + (size_t)(j0 + jr) * (NG * HD) + g * HD + k0 + c4);
        As[ar][ac + 0] = av.x; As[ar][ac + 1] = av.y;
        As[ar][ac + 2] = av.z; As[ar][ac + 3] = av.w;
        Bs[c4 + 0][jr] = bv.x; Bs[c4 + 1][jr] = bv.y;
        Bs[c4 + 2][jr] = bv.z; Bs[c4 + 3][jr] = bv.w;
        __syncthreads();
        #pragma unroll
        for (int kk = 0; kk < 16; kk++) {
            float a[4], b[4];
            #pragma unroll
            for (int i = 0; i < 4; i++) a[i] = As[ty * 4 + i][kk];
            #pragma unroll
            for (int j = 0; j < 4; j++) b[j] = Bs[kk][tx * 4 + j];
            #pragma unroll
            for (int i = 0; i < 4; i++)
                #pragma unroll
                for (int j = 0; j < 4; j++) acc[i][j] += a[i] * b[j];
        }
        __syncthreads();
    }
    #pragma unroll
    for (int i = 0; i < 4; i++) {
        float4 ov = make_float4(acc[i][0] * scale, acc[i][1] * scale,
                                acc[i][2] * scale, acc[i][3] * scale);
        *(float4*)(P + ((size_t)h * S + i0 + ty * 4 + i) * S + j0 + tx * 4) = ov;
    }
}

// Per (row i, head h): causal softmax in place on P row (raw scores -> probs),
// zeros above the diagonal.
__global__ __launch_bounds__(256) void softmax_kernel(float* __restrict__ P)
{
    __shared__ float red[256];
    int i = blockIdx.x, h = blockIdx.y;
    int tid = threadIdx.x;
    float* row = P + ((size_t)h * S + i) * S;
    float m = -1e30f;
    for (int j = tid; j <= i; j += 256) m = fmaxf(m, row[j]);
    red[tid] = m; __syncthreads();
    for (int st = 128; st > 0; st >>= 1) {
        if (tid < st) red[tid] = fmaxf(red[tid], red[tid + st]);
        __syncthreads();
    }
    m = red[0]; __syncthreads();
    float sum = 0.f;
    for (int j = tid; j <= i; j += 256) {
        float e = __expf(row[j] - m);
        row[j] = e; sum += e;
    }
    red[tid] = sum; __syncthreads();
    for (int st = 128; st > 0; st >>= 1) {
        if (tid < st) red[tid] += red[tid + st];
        __syncthreads();
    }
    float inv = 1.0f / red[0];
    __syncthreads();  // all e-stores visible before cross-thread read-back
    for (int b = tid * 4; b < S; b += 1024) {
        float4 v = *(const float4*)(row + b);
        float4 ov;
        ov.x = (b     <= i) ? v.x * inv : 0.0f;
        ov.y = (b + 1 <= i) ? v.y * inv : 0.0f;
        ov.z = (b + 2 <= i) ? v.z * inv : 0.0f;
        ov.w = (b + 3 <= i) ? v.w * inv : 0.0f;
        *(float4*)(row + b) = ov;
    }
}

// O[i][h*HD + d] = sum_j P[h][i][j] * V[j][g*HD + d]. Skips all-zero K-tiles
// past the diagonal.
__global__ __launch_bounds__(256) void pv_kernel(const float* __restrict__ P,
                                                 const float* __restrict__ V,
                                                 float* __restrict__ O)
{
    int ct = blockIdx.x, it = blockIdx.y, h = blockIdx.z;
    int g = h >> 2;
    int i0 = it * 64, c0 = ct * 64;
    __shared__ float As[64][16];
    __shared__ float Bs[16][64];
    int tid = threadIdx.x;
    int tx = tid & 15, ty = tid >> 4;
    float acc[4][4] = {};
    int ae = tid * 4; int ar = ae >> 4, ac = ae & 15;
    int be = tid * 4; int br = be >> 6, bc = be & 63;
    const float* Ph = P + (size_t)h * S * S;
    int kend = i0 + 64;  // P[i][j] == 0 for j > i
    for (int k0 = 0; k0 < kend; k0 += 16) {
        float4 av = *(const float4*)(Ph + (size_t)(i0 + ar) * S + k0 + ac);
        float4 bv = *(const float4*)(V + (size_t)(k0 + br) * (NG * HD) + g * HD + c0 + bc);
        As[ar][ac + 0] = av.x; As[ar][ac + 1] = av.y;
        As[ar][ac + 2] = av.z; As[ar][ac + 3] = av.w;
        Bs[br][bc + 0] = bv.x; Bs[br][bc + 1] = bv.y;
        Bs[br][bc + 2] = bv.z; Bs[br][bc + 3] = bv.w;
        __syncthreads();
        #pragma unroll
        for (int kk = 0; kk < 16; kk++) {
            float a[4], b[4];
            #pragma unroll
            for (int i = 0; i < 4; i++) a[i] = As[ty * 4 + i][kk];
            #pragma unroll
            for (int j = 0; j < 4; j++) b[j] = Bs[kk][tx * 4 + j];
            #pragma unroll
            for (int i = 0; i < 4; i++)
                #pragma unroll
                for (int j = 0; j < 4; j++) acc[i][j] += a[i] * b[j];
        }
        __syncthreads();
    }
    #pragma unroll
    for (int i = 0; i < 4; i++) {
        float4 ov = make_float4(acc[i][0], acc[i][1], acc[i][2], acc[i][3]);
        *(float4*)(O + (size_t)(i0 + ty * 4 + i) * E + h * HD + c0 + tx * 4) = ov;
    }
}

extern "C" void kernel_launch(void* const* d_in, const int* in_sizes, int n_in,
                              void* d_out, int out_size, void* d_ws, size_t ws_size,
                              hipStream_t stream)
{
    const float* x    = (const float*)d_in[0];
    // d_in[1] = mask: causal triu(k=1), implemented analytically — unused.
    const float* cosp = (const float*)d_in[2];
    const float* sinp = (const float*)d_in[3];
    const float* Wq   = (const float*)d_in[4];
    const float* Wk   = (const float*)d_in[5];
    const float* Wv   = (const float*)d_in[6];
    const float* Wout = (const float*)d_in[7];

    float* out0 = (float*)d_out;               // (S, E) fp32
    float* Pout = out0 + (size_t)S * E;        // (NH, S, S) fp32

    float* Qb = (float*)d_ws;                  // S*E        fp32 (16 MB)
    float* Kb = Qb + (size_t)S * E;            // S*NG*HD    fp32 ( 4 MB)
    float* Vb = Kb + (size_t)S * NG * HD;      // S*NG*HD    fp32 ( 4 MB)
    float* Ob = Vb + (size_t)S * NG * HD;      // S*E        fp32 (16 MB)

    dim3 blk(256);
    gemm_f32<<<dim3(E / 64, S / 64), blk, 0, stream>>>(x, Wq, Qb, S, E, E);
    gemm_f32<<<dim3((NG * HD) / 64, S / 64), blk, 0, stream>>>(x, Wk, Kb, S, NG * HD, E);
    gemm_f32<<<dim3((NG * HD) / 64, S / 64), blk, 0, stream>>>(x, Wv, Vb, S, NG * HD, E);

    int totQ = S * NH * 64;
    rope_kernel<<<(totQ + 255) / 256, blk, 0, stream>>>(Qb, cosp, sinp, NH, totQ);
    int totK = S * NG * 64;
    rope_kernel<<<(totK + 255) / 256, blk, 0, stream>>>(Kb, cosp, sinp, NG, totK);

    score_kernel<<<dim3(S / 64, S / 64, NH), blk, 0, stream>>>(Qb, Kb, Pout);
    softmax_kernel<<<dim3(S, NH), blk, 0, stream>>>(Pout);
    pv_kernel<<<dim3(HD / 64, S / 64, NH), blk, 0, stream>>>(Pout, Vb, Ob);

    gemm_f32<<<dim3(E / 64, S / 64), blk, 0, stream>>>(Ob, Wout, out0, S, E, E);
}

// Round 5
// 785.001 us; speedup vs baseline: 6.6339x; 2.2934x over previous
//
#include <hip/hip_runtime.h>
#include <stdint.h>

#define S 2048
#define E 2048
#define NH 16
#define NG 4
#define HD 128
#define LDSTR 40   // LDS row stride (bf16 elems): 32 data + 8 pad -> conflict-free b128

using short8 = __attribute__((ext_vector_type(8))) short;  // 8 bf16 (4 VGPRs)
using f32x4  = __attribute__((ext_vector_type(4))) float;  // 4 fp32 acc

__device__ __forceinline__ unsigned short f2bf(float f){
    union { float f; unsigned int i; } v; v.f = f;
    unsigned int x = v.i;
    unsigned int r = x + 0x7FFFu + ((x >> 16) & 1u);  // round-to-nearest-even
    return (unsigned short)(r >> 16);
}

// Stage 8 contiguous elements into LDS as bf16 (16B store).
__device__ __forceinline__ void stage8(const float* gp, unsigned short* lp){
    float4 a = *(const float4*)gp;
    float4 b = *(const float4*)(gp + 4);
    unsigned int w0 = (unsigned int)f2bf(a.x) | ((unsigned int)f2bf(a.y) << 16);
    unsigned int w1 = (unsigned int)f2bf(a.z) | ((unsigned int)f2bf(a.w) << 16);
    unsigned int w2 = (unsigned int)f2bf(b.x) | ((unsigned int)f2bf(b.y) << 16);
    unsigned int w3 = (unsigned int)f2bf(b.z) | ((unsigned int)f2bf(b.w) << 16);
    *(uint4*)lp = make_uint4(w0, w1, w2, w3);
}
__device__ __forceinline__ void stage8(const unsigned short* gp, unsigned short* lp){
    *(uint4*)lp = *(const uint4*)gp;
}

// Core: C128x128 tile += A[128 x K] * Bt[128 x K]^T, MFMA 16x16x32 bf16.
// A row-major [rows][lda] (k contiguous), Bt row-major [cols][ldb] (k contiguous).
template<typename TA, typename TB>
__device__ __forceinline__ void gemm_core(const TA* __restrict__ At, int lda,
                                          const TB* __restrict__ Bt, int ldb,
                                          int K, f32x4 acc[4][4],
                                          unsigned short* lA, unsigned short* lB)
{
    int tid = threadIdx.x;
    int wave = tid >> 6, lane = tid & 63;
    int mBase = (wave >> 1) * 64, nBase = (wave & 1) * 64;
    int rowA = lane & 15, kq = (lane >> 4) * 8;
    for (int k0 = 0; k0 < K; k0 += 32) {
        __syncthreads();   // previous iter's LDS fully consumed
        #pragma unroll
        for (int c = 0; c < 2; c++) {
            int idx = tid + c * 256;       // 0..511
            int r = idx >> 2, q = idx & 3; // 128 rows x 4 chunks of 8
            stage8(At + (size_t)r * lda + k0 + q * 8, lA + r * LDSTR + q * 8);
            stage8(Bt + (size_t)r * ldb + k0 + q * 8, lB + r * LDSTR + q * 8);
        }
        __syncthreads();
        short8 af[4], bf[4];
        #pragma unroll
        for (int i = 0; i < 4; i++)
            af[i] = *(const short8*)&lA[(mBase + i * 16 + rowA) * LDSTR + kq];
        #pragma unroll
        for (int j = 0; j < 4; j++)
            bf[j] = *(const short8*)&lB[(nBase + j * 16 + rowA) * LDSTR + kq];
        #pragma unroll
        for (int i = 0; i < 4; i++)
            #pragma unroll
            for (int j = 0; j < 4; j++)
                acc[i][j] = __builtin_amdgcn_mfma_f32_16x16x32_bf16(af[i], bf[j], acc[i][j], 0, 0, 0);
    }
}

// C/D layout: col = lane&15, row = (lane>>4)*4 + reg.
template<bool BF16OUT>
__device__ __forceinline__ void epilogue(f32x4 acc[4][4], void* Cv, int ldc,
                                         int row0, int col0, float scale)
{
    int tid = threadIdx.x, wave = tid >> 6, lane = tid & 63;
    int mBase = (wave >> 1) * 64, nBase = (wave & 1) * 64;
    int col = lane & 15, quad = lane >> 4;
    #pragma unroll
    for (int i = 0; i < 4; i++)
        #pragma unroll
        for (int j = 0; j < 4; j++)
            #pragma unroll
            for (int r = 0; r < 4; r++) {
                int gr = row0 + mBase + i * 16 + quad * 4 + r;
                int gc = col0 + nBase + j * 16 + col;
                float v = acc[i][j][r] * scale;
                if (BF16OUT) ((unsigned short*)Cv)[(size_t)gr * ldc + gc] = f2bf(v);
                else         ((float*)Cv)[(size_t)gr * ldc + gc] = v;
            }
}

template<typename TA, bool BF16OUT>
__global__ __launch_bounds__(256) void gemm_mfma(const TA* __restrict__ A, int lda,
                                                 const unsigned short* __restrict__ Bt, int ldb,
                                                 void* __restrict__ C, int ldc, int K)
{
    __shared__ unsigned short lA[128 * LDSTR];
    __shared__ unsigned short lB[128 * LDSTR];
    int row0 = blockIdx.y * 128, col0 = blockIdx.x * 128;
    f32x4 acc[4][4] = {};
    gemm_core(A + (size_t)row0 * lda, lda, Bt + (size_t)col0 * ldb, ldb, K, acc, lA, lB);
    epilogue<BF16OUT>(acc, C, ldc, row0, col0, 1.0f);
}

// scores = scale * Q_h . K_g^T  (raw, unmasked; causal-skipped tiles stay unwritten)
__global__ __launch_bounds__(256) void score_mfma(const unsigned short* __restrict__ Q,
                                                  const unsigned short* __restrict__ Kb,
                                                  float* __restrict__ P)
{
    int jt = blockIdx.x, it = blockIdx.y, h = blockIdx.z;
    if (jt > it) return;
    __shared__ unsigned short lA[128 * LDSTR];
    __shared__ unsigned short lB[128 * LDSTR];
    f32x4 acc[4][4] = {};
    gemm_core(Q + (size_t)(it * 128) * E + h * HD, E,
              Kb + (size_t)(jt * 128) * (NG * HD) + (h >> 2) * HD, NG * HD,
              HD, acc, lA, lB);
    epilogue<false>(acc, P + (size_t)h * S * S, S, it * 128, jt * 128,
                    0.08838834764831845f);  // 1/sqrt(128)
}

// O_h = P_h @ V_g  (K truncated at the causal diagonal), bf16 out
__global__ __launch_bounds__(256) void pv_mfma(const float* __restrict__ P,
                                               const unsigned short* __restrict__ Vt,
                                               unsigned short* __restrict__ Obf)
{
    int it = blockIdx.y, h = blockIdx.z;
    __shared__ unsigned short lA[128 * LDSTR];
    __shared__ unsigned short lB[128 * LDSTR];
    f32x4 acc[4][4] = {};
    gemm_core(P + (size_t)h * S * S + (size_t)(it * 128) * S, S,
              Vt + (size_t)((h >> 2) * HD) * S, S,
              (it + 1) * 128, acc, lA, lB);
    epilogue<true>(acc, Obf, E, it * 128, h * HD, 1.0f);
}

// fp32 in[R][C] -> bf16 out[C][R]
__global__ __launch_bounds__(256) void transpose_cvt(const float* __restrict__ in,
                                                     unsigned short* __restrict__ out,
                                                     int R, int C)
{
    __shared__ float t[32][33];
    int r0 = blockIdx.y * 32, c0 = blockIdx.x * 32;
    int tid = threadIdx.x;
    int rr = tid >> 3, cc = (tid & 7) * 4;
    float4 v = *(const float4*)(in + (size_t)(r0 + rr) * C + c0 + cc);
    t[rr][cc] = v.x; t[rr][cc + 1] = v.y; t[rr][cc + 2] = v.z; t[rr][cc + 3] = v.w;
    __syncthreads();
    int oc = tid >> 3, orr = (tid & 7) * 4;
    ushort4 o;
    o.x = f2bf(t[orr][oc]);     o.y = f2bf(t[orr + 1][oc]);
    o.z = f2bf(t[orr + 2][oc]); o.w = f2bf(t[orr + 3][oc]);
    *(ushort4*)(out + (size_t)(c0 + oc) * R + r0 + orr) = o;
}

// RoPE fp32 -> bf16: out_d = x_d*c - x_{d+64}*s ; out_{d+64} = x_{d+64}*c + x_d*s
__global__ void rope_bf16(const float* __restrict__ T, unsigned short* __restrict__ Tb,
                          const float* __restrict__ cosp, const float* __restrict__ sinp,
                          int nHeads, int total)
{
    int idx = blockIdx.x * blockDim.x + threadIdx.x;
    if (idx >= total) return;
    int d = idx & 63;
    int head = (idx >> 6) % nHeads;
    int s = idx / (nHeads * 64);
    float c  = cosp[s * HD + d];   // cos[s][d] == cos[s][d+64]
    float sn = sinp[s * HD + d];
    size_t base = (size_t)s * nHeads * HD + head * HD + d;
    float x1 = T[base], x2 = T[base + 64];
    Tb[base]      = f2bf(x1 * c - x2 * sn);
    Tb[base + 64] = f2bf(x2 * c + x1 * sn);
}

// Per (row i, head h): causal softmax in place, row cached in LDS.
__global__ __launch_bounds__(256) void softmax_kernel(float* __restrict__ P)
{
    __shared__ float rowv[S];
    __shared__ float red[256];
    int i = blockIdx.x, h = blockIdx.y;
    int tid = threadIdx.x;
    float* row = P + ((size_t)h * S + i) * S;
    float m = -1e30f;
    for (int b = tid * 4; b <= i; b += 1024) {
        float4 v = *(const float4*)(row + b);
        rowv[b] = v.x; rowv[b + 1] = v.y; rowv[b + 2] = v.z; rowv[b + 3] = v.w;
        m = fmaxf(m, v.x);
        if (b + 1 <= i) m = fmaxf(m, v.y);
        if (b + 2 <= i) m = fmaxf(m, v.z);
        if (b + 3 <= i) m = fmaxf(m, v.w);
    }
    red[tid] = m; __syncthreads();
    for (int st = 128; st > 0; st >>= 1) {
        if (tid < st) red[tid] = fmaxf(red[tid], red[tid + st]);
        __syncthreads();
    }
    m = red[0]; __syncthreads();
    float sum = 0.f;
    for (int j = tid; j <= i; j += 256) {
        float e = __expf(rowv[j] - m);
        rowv[j] = e; sum += e;
    }
    red[tid] = sum; __syncthreads();
    for (int st = 128; st > 0; st >>= 1) {
        if (tid < st) red[tid] += red[tid + st];
        __syncthreads();
    }
    float inv = 1.0f / red[0];
    __syncthreads();
    for (int b = tid * 4; b < S; b += 1024) {
        float4 ov;
        ov.x = (b     <= i) ? rowv[b]     * inv : 0.0f;
        ov.y = (b + 1 <= i) ? rowv[b + 1] * inv : 0.0f;
        ov.z = (b + 2 <= i) ? rowv[b + 2] * inv : 0.0f;
        ov.w = (b + 3 <= i) ? rowv[b + 3] * inv : 0.0f;
        *(float4*)(row + b) = ov;
    }
}

extern "C" void kernel_launch(void* const* d_in, const int* in_sizes, int n_in,
                              void* d_out, int out_size, void* d_ws, size_t ws_size,
                              hipStream_t stream)
{
    const float* x    = (const float*)d_in[0];
    // d_in[1] = mask: causal triu(k=1), implemented analytically — unused.
    const float* cosp = (const float*)d_in[2];
    const float* sinp = (const float*)d_in[3];
    const float* Wq   = (const float*)d_in[4];
    const float* Wk   = (const float*)d_in[5];
    const float* Wv   = (const float*)d_in[6];
    const float* Wout = (const float*)d_in[7];

    float* out0 = (float*)d_out;               // (S, E) fp32
    float* Pout = out0 + (size_t)S * E;        // (NH, S, S) fp32

    // Workspace layout (64 MB total)
    unsigned short* Wqt   = (unsigned short*)d_ws;        // [2048][2048] bf16 Wq^T
    unsigned short* Woutt = Wqt   + (size_t)E * E;        // [2048][2048] bf16 Wout^T
    unsigned short* Wkt   = Woutt + (size_t)E * E;        // [512][2048]  bf16 Wk^T
    unsigned short* Wvt   = Wkt   + (size_t)(NG * HD) * E;// [512][2048]  bf16 Wv^T
    unsigned short* Qbf   = Wvt   + (size_t)(NG * HD) * E;// [2048][2048] bf16 roped Q
    unsigned short* Kbf   = Qbf   + (size_t)S * E;        // [2048][512]  bf16 roped K
    unsigned short* Vt    = Kbf   + (size_t)S * (NG * HD);// [512][2048]  bf16 V^T
    unsigned short* Obf   = Vt    + (size_t)(NG * HD) * S;// [2048][2048] bf16 attn out
    float* Qb = (float*)(Obf + (size_t)S * E);            // fp32 Q pre-rope
    float* Kb = Qb + (size_t)S * E;                       // fp32 K pre-rope
    float* Vb = Kb + (size_t)S * (NG * HD);               // fp32 V

    dim3 blk(256);
    // Weight transpose + bf16 cast (per-launch; ~66 MB traffic total)
    transpose_cvt<<<dim3(E / 32, E / 32), blk, 0, stream>>>(Wq, Wqt, E, E);
    transpose_cvt<<<dim3((NG * HD) / 32, E / 32), blk, 0, stream>>>(Wk, Wkt, E, NG * HD);
    transpose_cvt<<<dim3((NG * HD) / 32, E / 32), blk, 0, stream>>>(Wv, Wvt, E, NG * HD);
    transpose_cvt<<<dim3(E / 32, E / 32), blk, 0, stream>>>(Wout, Woutt, E, E);

    // Projections (MFMA, fp32 A staged-converted)
    gemm_mfma<float, false><<<dim3(E / 128, S / 128), blk, 0, stream>>>(x, E, Wqt, E, Qb, E, E);
    gemm_mfma<float, false><<<dim3((NG * HD) / 128, S / 128), blk, 0, stream>>>(x, E, Wkt, E, Kb, NG * HD, E);
    gemm_mfma<float, false><<<dim3((NG * HD) / 128, S / 128), blk, 0, stream>>>(x, E, Wvt, E, Vb, NG * HD, E);

    // RoPE -> bf16 Q/K
    rope_bf16<<<(S * NH * 64 + 255) / 256, blk, 0, stream>>>(Qb, Qbf, cosp, sinp, NH, S * NH * 64);
    rope_bf16<<<(S * NG * 64 + 255) / 256, blk, 0, stream>>>(Kb, Kbf, cosp, sinp, NG, S * NG * 64);
    // V^T bf16
    transpose_cvt<<<dim3((NG * HD) / 32, S / 32), blk, 0, stream>>>(Vb, Vt, S, NG * HD);

    // Attention
    score_mfma<<<dim3(S / 128, S / 128, NH), blk, 0, stream>>>(Qbf, Kbf, Pout);
    softmax_kernel<<<dim3(S, NH), blk, 0, stream>>>(Pout);
    pv_mfma<<<dim3(1, S / 128, NH), blk, 0, stream>>>(Pout, Vt, Obf);

    // Output projection
    gemm_mfma<unsigned short, false><<<dim3(E / 128, S / 128), blk, 0, stream>>>(Obf, E, Woutt, E, out0, E, E);
}